// Round 7
// baseline (182.285 us; speedup 1.0000x reference)
//
#include <hip/hip_runtime.h>
#include <hip/hip_fp16.h>
#include <math.h>

// Problem constants: B=4, M=4096, D=64, W=128
constexpr int B = 4;
constexpr int M = 4096;
constexpr int D = 64;
constexpr int W = 128;
constexpr int NELEM = B * M * D;

constexpr int TT  = 64;        // k-rows per tile
constexpr int NTT = M / TT;    // 64 tiles
constexpr int RB  = 64;        // m-rows per block

typedef _Float16 h2_t __attribute__((ext_vector_type(2)));
typedef int      i4_t __attribute__((ext_vector_type(4)));
typedef int      i2_t __attribute__((ext_vector_type(2)));

typedef __attribute__((address_space(1))) const void* gptr_t;
typedef __attribute__((address_space(3))) void*       sptr_t;

// ---- pass 1: fp32 -> fp16 of k AND v ----
__global__ __launch_bounds__(256) void cvt_f32_f16_2(
    const float4* __restrict__ k, const float4* __restrict__ v,
    __half2* __restrict__ kh, __half2* __restrict__ vh, int n4) {
    int i = blockIdx.x * 256 + threadIdx.x;
    const float4* src;
    __half2* dst;
    if (i < n4) { src = k; dst = kh; }
    else        { src = v; dst = vh; i -= n4; if (i >= n4) return; }
    float4 f = src[i];
    dst[2 * i]     = __floats2half2_rn(f.x, f.y);
    dst[2 * i + 1] = __floats2half2_rn(f.z, f.w);
}

// ---- pass 2: per-row tile-sort (by idx>>6) of the 128 indices, written
// TRANSPOSED: idx2t[pos * M + m]. Transposed layout lets the main kernel
// stage its 64-row slice with one global_load_lds per wave and read
// per-position entries as LDS broadcasts. Order within a tile is arbitrary
// (softmax+PV is permutation-invariant in w); idx is shared across batches.
__global__ __launch_bounds__(256) void bucket_idx_t(
    const int* __restrict__ idx, unsigned short* __restrict__ idx2t) {
    const int m    = blockIdx.x * 4 + (threadIdx.x >> 6);
    const int lane = threadIdx.x & 63;
    const int* row = idx + (size_t)m * W;
    const int j0 = row[lane], j1 = row[lane + 64];
    const int b0 = j0 >> 6,   b1 = j1 >> 6;
    const unsigned long long lt = (1ULL << lane) - 1ULL;
    int base = 0;
    for (int t = 0; t < NTT; ++t) {
        const unsigned long long q0 = __ballot(b0 == t);
        const unsigned long long q1 = __ballot(b1 == t);
        const int c0 = __popcll(q0);
        if (b0 == t)
            idx2t[(size_t)(base + __popcll(q0 & lt)) * M + m] = (unsigned short)j0;
        if (b1 == t)
            idx2t[(size_t)(base + c0 + __popcll(q1 & lt)) * M + m] = (unsigned short)j1;
        base += c0 + __popcll(q1);
    }
}

// cross-lane adds: DPP for xor1/xor2 (quad_perm) and xor8 (row_ror:8 —
// rotation by half the 16-lane row == xor8); ds_swizzle only for xor4.
template <int CTRL>
__device__ __forceinline__ float dpp_add(float x) {
    const int yi = __builtin_amdgcn_update_dpp(
        0, __builtin_bit_cast(int, x), CTRL, 0xF, 0xF, true);
    return x + __builtin_bit_cast(float, yi);
}
template <int PAT>
__device__ __forceinline__ float swz_add(float x) {
    const int yi = __builtin_amdgcn_ds_swizzle(__builtin_bit_cast(int, x), PAT);
    return x + __builtin_bit_cast(float, yi);
}

// ---- main kernel: dense-streamed K/V ring + sorted-window consumption.
// R4 post-mortem: streaming kills the gather bottleneck (FETCH 9 MB) but
// the consumer was latency-bound (VALUBusy 27%, 2 waves/SIMD, 90-cy shfl
// reduce per entry, divergent buckets). This version:
//  * 16 lanes per m-row (4 dims each): logit reduce = quad_perm xor1/xor2
//    + row_ror:8 (all VALU DPP) + ONE ds_swizzle (xor4) — ~12 cy.
//  * entries tile-sorted per row; groups consume their sorted streams
//    inside a residency window [t, t+1] — balanced, ~128 iters/row.
//  * 1024-thr block, 64 rows, TT=64 tiles, 4-slot ring (64 KB) + idx 16 KB
//    = 80 KB LDS -> 16 waves/CU = 4/SIMD (2x R4 occupancy).
//  * cross-wave staging correctness: own-loads vmcnt(0) BEFORE s_barrier
//    (per-wave vmcnt + barrier => all waves' loads complete; a
//    vmcnt-after-barrier ordering would race). stage(t+2) issues at loop
//    top so its latency hides under the whole consume phase.
//  * K/V rows swizzled in 16-B slots by row&7 (pre-swizzled global source,
//    swizzled LDS read — both-sides rule).
__global__ __launch_bounds__(1024, 4) void sparse_attn_win(
    const float* __restrict__ q,
    const __half* __restrict__ kh,
    const __half* __restrict__ vh,
    const unsigned short* __restrict__ idx2t,
    float* __restrict__ out)
{
    const int blk  = blockIdx.x;
    const int b    = blk & 3;              // XCD pinning: 2 XCDs per batch
    const int mc   = blk >> 2;             // 0..63
    const int tid  = threadIdx.x;
    const int wave = tid >> 6;             // 0..15
    const int lane = tid & 63;
    const int g    = lane >> 4;            // group (row) within wave: 0..3
    const int c    = lane & 15;            // dim-chunk: dims [c*4, c*4+4)
    const int rl   = wave * 4 + g;         // 0..63 local row
    const int m    = mc * RB + rl;

    __shared__ i4_t ring_k[4][TT][8];                          // 32 KB
    __shared__ i4_t ring_v[4][TT][8];                          // 32 KB
    __shared__ __align__(16) unsigned short idx2_s[W][RB];     // 16 KB

    const char* kb = (const char*)(kh + (size_t)b * M * D);
    const char* vb = (const char*)(vh + (size_t)b * M * D);

    // staging: 1 global_load_lds per wave per tile (16 KB/tile total).
    // waves 0-7 stage K rows [8w,8w+8); waves 8-15 the same V rows.
    const int rsub = lane >> 3;            // 0..7
    const int scol = lane & 7;             // dest 16-B slot
    const int wh   = wave & 7;
    auto stage = [&](int u) {
        const int s = u & 3;
        const size_t go = ((size_t)(u * TT + wh * 8 + rsub)) * 128
                        + (size_t)((scol ^ rsub) * 16);   // pre-swizzled src
        if (wave < 8)
            __builtin_amdgcn_global_load_lds((gptr_t)(kb + go),
                (sptr_t)&ring_k[s][wh * 8][0], 16, 0, 0);
        else
            __builtin_amdgcn_global_load_lds((gptr_t)(vb + go),
                (sptr_t)&ring_v[s][wh * 8][0], 16, 0, 0);
    };

    // prologue: idx slice (1 instr/wave, transposed source) + tiles 0,1
    {
        const size_t so = ((size_t)(wave * 8 + rsub) * M
                         + (size_t)mc * RB + scol * 8) * 2;
        __builtin_amdgcn_global_load_lds((gptr_t)((const char*)idx2t + so),
            (sptr_t)&idx2_s[wave * 8][0], 16, 0, 0);
    }
    stage(0);
    stage(1);

    // q fragment: dims [c*4, c*4+4)
    const float4 qf = *(const float4*)(q + ((size_t)b * M + m) * D + c * 4);
    h2_t qh[2];
    qh[0] = (h2_t){(_Float16)qf.x, (_Float16)qf.y};
    qh[1] = (h2_t){(_Float16)qf.z, (_Float16)qf.w};

    asm volatile("s_waitcnt vmcnt(0)" ::: "memory");
    __syncthreads();                       // tiles 0,1 + idx resident (all waves)

    float acc[4] = {0.f, 0.f, 0.f, 0.f};
    float mrun = -1e30f;
    float l = 0.f;

    int pos = 0;
    int cur = idx2_s[0][rl];               // group-uniform broadcast read

    for (int t = 0; t < NTT; ++t) {
        if (t + 2 < NTT) stage(t + 2);     // slot (t+2)&3 == tile t-2's (dead)

        // consume: forced tile t, opportunistic t+1 (resident window)
        while (__any(pos < W && (cur >> 6) <= t)) {
            const bool adv = (pos < W) && ((cur >> 6) <= t + 1);
            if (adv) {
                const int pn  = (pos < W - 1) ? pos + 1 : W - 1;
                const int nxt = idx2_s[pn][rl];       // prefetch next entry
                const int r   = cur & (TT - 1);
                const int s   = (cur >> 6) & 3;
                // 8-B granule index with 16-B slot swizzle by row&7
                const int gr  = ((((c >> 1) ^ (r & 7)) << 1) | (c & 1));
                union { i2_t v; h2_t h[2]; } uk, uv;
                uk.v = ((const i2_t*)&ring_k[s][r][0])[gr];
                float part = __builtin_amdgcn_fdot2(uk.h[0], qh[0], 0.f, false);
                part = __builtin_amdgcn_fdot2(uk.h[1], qh[1], part, false);
                part = dpp_add<0xB1>(part);           // xor1 (quad_perm 1,0,3,2)
                part = dpp_add<0x4E>(part);           // xor2 (quad_perm 2,3,0,1)
                part = dpp_add<0x128>(part);          // xor8 (row_ror:8)
                part = swz_add<0x101F>(part);         // xor4 (ds_swizzle)
                float d = part - mrun;
                if (d > 8.0f) {                       // defer-max: rare rescale
                    const float sc_ = __expf(-d);
                    l *= sc_;
                    acc[0] *= sc_; acc[1] *= sc_;
                    acc[2] *= sc_; acc[3] *= sc_;
                    mrun = part;
                    d = 0.f;
                }
                const float pw = __expf(d);           // bounded by e^8
                l += pw;
                uv.v = ((const i2_t*)&ring_v[s][r][0])[gr];
                acc[0] += pw * (float)uv.h[0][0];
                acc[1] += pw * (float)uv.h[0][1];
                acc[2] += pw * (float)uv.h[1][0];
                acc[3] += pw * (float)uv.h[1][1];
                ++pos;
                cur = nxt;
            }
        }

        // own t+2 load done BEFORE barrier => after barrier, ALL waves'
        // t+2 loads are complete (this ordering is the correctness key).
        asm volatile("s_waitcnt vmcnt(0)" ::: "memory");
        __builtin_amdgcn_s_barrier();
        asm volatile("" ::: "memory");
    }

    const float inv = 1.0f / l;
    *(float4*)(out + ((size_t)b * M + m) * D + c * 4) =
        make_float4(acc[0] * inv, acc[1] * inv, acc[2] * inv, acc[3] * inv);
}

// ---- fallback fp32 kernel if workspace too small ----
__global__ __launch_bounds__(128) void sparse_attn_f32(
    const float* __restrict__ q,
    const float* __restrict__ k,
    const float* __restrict__ v,
    const int*   __restrict__ idx,
    float*       __restrict__ out)
{
    const int blk = blockIdx.x;
    const int b = blk & 3;
    const int m = blk >> 2;
    const int t = threadIdx.x;
    const int lane = t & 63;
    const int wave = t >> 6;
    const int ci = lane & 15;
    const int r  = lane >> 4;

    __shared__ int   idx_s[W];
    __shared__ float sc_s[W];
    __shared__ float red_s[4];
    __shared__ float4 opart_s[16];

    idx_s[t] = idx[m * W + t];
    const float4 qf = ((const float4*)(q + ((size_t)b * M + m) * D))[ci];
    __syncthreads();

    const float* kb = k + (size_t)b * M * D;
    const int wbase = wave * 64;

    #pragma unroll
    for (int j = 0; j < 16; ++j) {
        const int w = wbase + j * 4 + r;
        const float4 kv = ((const float4*)(kb + (size_t)idx_s[w] * D))[ci];
        float part = kv.x * qf.x + kv.y * qf.y + kv.z * qf.z + kv.w * qf.w;
        part += __shfl_xor(part, 1);
        part += __shfl_xor(part, 2);
        part += __shfl_xor(part, 4);
        part += __shfl_xor(part, 8);
        if (ci == 0) sc_s[w] = part;
    }
    __syncthreads();

    float logit = sc_s[t];
    float mx = logit;
    #pragma unroll
    for (int o = 1; o < 64; o <<= 1) mx = fmaxf(mx, __shfl_xor(mx, o));
    if (lane == 0) red_s[wave] = mx;
    __syncthreads();
    mx = fmaxf(red_s[0], red_s[1]);
    float e = __expf(logit - mx);
    float sm = e;
    #pragma unroll
    for (int o = 1; o < 64; o <<= 1) sm += __shfl_xor(sm, o);
    if (lane == 0) red_s[2 + wave] = sm;
    __syncthreads();
    const float inv_denom = 1.0f / (red_s[2] + red_s[3]);
    sc_s[t] = e * inv_denom;
    __syncthreads();

    const float* vb = v + (size_t)b * M * D;
    float4 acc = {0.f, 0.f, 0.f, 0.f};
    #pragma unroll
    for (int j = 0; j < 16; ++j) {
        const int w = wbase + j * 4 + r;
        const float p = sc_s[w];
        const float4 vv = ((const float4*)(vb + (size_t)idx_s[w] * D))[ci];
        acc.x += p * vv.x; acc.y += p * vv.y;
        acc.z += p * vv.z; acc.w += p * vv.w;
    }
    acc.x += __shfl_xor(acc.x, 16); acc.y += __shfl_xor(acc.y, 16);
    acc.z += __shfl_xor(acc.z, 16); acc.w += __shfl_xor(acc.w, 16);
    acc.x += __shfl_xor(acc.x, 32); acc.y += __shfl_xor(acc.y, 32);
    acc.z += __shfl_xor(acc.z, 32); acc.w += __shfl_xor(acc.w, 32);

    if (wave == 0 && r == 0) opart_s[ci] = acc;
    __syncthreads();
    if (wave == 1 && r == 0) {
        const float4 o0 = opart_s[ci];
        float4 res;
        res.x = o0.x + acc.x; res.y = o0.y + acc.y;
        res.z = o0.z + acc.z; res.w = o0.w + acc.w;
        ((float4*)(out + ((size_t)b * M + m) * D))[ci] = res;
    }
}

extern "C" void kernel_launch(void* const* d_in, const int* in_sizes, int n_in,
                              void* d_out, int out_size, void* d_ws, size_t ws_size,
                              hipStream_t stream) {
    const float* q = (const float*)d_in[0];
    const float* k = (const float*)d_in[1];
    const float* v = (const float*)d_in[2];
    const int* idx = (const int*)d_in[3];
    float* out = (float*)d_out;

    // workspace: kh (2 MB) | vh (2 MB) | idx2t u16 transposed (1 MB)
    const size_t sz_kv   = (size_t)NELEM * sizeof(__half);
    const size_t sz_idx2 = (size_t)M * W * sizeof(unsigned short);
    const size_t need = 2 * sz_kv + sz_idx2;
    if (ws_size >= need) {
        __half* khp = (__half*)d_ws;
        __half* vhp = khp + NELEM;
        unsigned short* idx2t = (unsigned short*)((char*)d_ws + 2 * sz_kv);

        const int n4 = NELEM / 4;
        const int cblk = (2 * n4 + 255) / 256;
        cvt_f32_f16_2<<<cblk, 256, 0, stream>>>((const float4*)k, (const float4*)v,
                                                (__half2*)khp, (__half2*)vhp, n4);
        bucket_idx_t<<<M / 4, 256, 0, stream>>>(idx, idx2t);
        sparse_attn_win<<<B * M / RB, 1024, 0, stream>>>(q, khp, vhp, idx2t, out);
    } else {
        sparse_attn_f32<<<B * M, 128, 0, stream>>>(q, k, v, idx, out);
    }
}

// Round 10
// 147.114 us; speedup vs baseline: 1.2391x; 1.2391x over previous
//
#include <hip/hip_runtime.h>
#include <hip/hip_fp16.h>
#include <math.h>

// Problem constants: B=4, M=4096, D=64, W=128
constexpr int B = 4;
constexpr int M = 4096;
constexpr int D = 64;
constexpr int W = 128;
constexpr int NELEM = B * M * D;

constexpr int TT  = 128;       // k-rows per tile
constexpr int NTT = M / TT;    // 32 tiles
constexpr int RB  = 64;        // m-rows per block

typedef _Float16 h2_t __attribute__((ext_vector_type(2)));
typedef int      i4_t __attribute__((ext_vector_type(4)));

typedef __attribute__((address_space(1))) const void* gptr_t;
typedef __attribute__((address_space(3))) void*       sptr_t;

// ---- pass 1: fp32 -> fp16 of k AND v ----
__global__ __launch_bounds__(256) void cvt_f32_f16_2(
    const float4* __restrict__ k, const float4* __restrict__ v,
    __half2* __restrict__ kh, __half2* __restrict__ vh, int n4) {
    int i = blockIdx.x * 256 + threadIdx.x;
    const float4* src;
    __half2* dst;
    if (i < n4) { src = k; dst = kh; }
    else        { src = v; dst = vh; i -= n4; if (i >= n4) return; }
    float4 f = src[i];
    dst[2 * i]     = __floats2half2_rn(f.x, f.y);
    dst[2 * i + 1] = __floats2half2_rn(f.z, f.w);
}

// ---- pass 2: per-row tile-sort (by idx>>7, TT=128) of the 128 indices,
// written TRANSPOSED: idx2t[pos * M + m]. Order within a tile arbitrary
// (softmax+PV permutation-invariant); idx shared across batches.
__global__ __launch_bounds__(256) void bucket_idx_t(
    const int* __restrict__ idx, unsigned short* __restrict__ idx2t) {
    const int m    = blockIdx.x * 4 + (threadIdx.x >> 6);
    const int lane = threadIdx.x & 63;
    const int* row = idx + (size_t)m * W;
    const int j0 = row[lane], j1 = row[lane + 64];
    const int b0 = j0 >> 7,   b1 = j1 >> 7;
    const unsigned long long lt = (1ULL << lane) - 1ULL;
    int base = 0;
    for (int t = 0; t < NTT; ++t) {
        const unsigned long long q0 = __ballot(b0 == t);
        const unsigned long long q1 = __ballot(b1 == t);
        const int c0 = __popcll(q0);
        if (b0 == t)
            idx2t[(size_t)(base + __popcll(q0 & lt)) * M + m] = (unsigned short)j0;
        if (b1 == t)
            idx2t[(size_t)(base + c0 + __popcll(q1 & lt)) * M + m] = (unsigned short)j1;
        base += c0 + __popcll(q1);
    }
}

// all-DPP 8-lane reduction: xor1/xor2 via quad_perm, cross-quad fold via
// row_half_mirror (0x141: lane i <-> 7-i within each 8-lane half; after
// the two quad_perm steps all quad lanes are equal, so mirror completes
// the 8-sum). Zero DS-pipe ops. adv is group-uniform so all DPP source
// lanes within an active 8-lane group are active.
template <int CTRL>
__device__ __forceinline__ float dpp_add(float x) {
    const int yi = __builtin_amdgcn_update_dpp(
        0, __builtin_bit_cast(int, x), CTRL, 0xF, 0xF, true);
    return x + __builtin_bit_cast(float, yi);
}

// ---- main kernel: dense-streamed K/V ring + sorted-window consumption,
// 8 ENTRIES per wave-iteration. R7 post-mortem: VALU-bound (60% busy,
// ~40 inst per 4-entry iteration). Changes:
//  * 8 lanes/row, 8 dims/lane, 8 rows/wave: ds_read_b128 K/V (full 128-B
//    row per group => all 32 banks covered, no swizzle needed), 4 fdot2,
//    3-op all-DPP reduce — same ~38 inst now cover 8 entries.
//  * TT=128 (32 tiles), 3-slot ring 96 KB + idx 16 KB = 112 KB, 512 thr,
//    grid 256 = 1 block/CU. stage(t+2) issues at loop top, lands during
//    consume(t); own vmcnt(0) BEFORE bottom barrier (cross-wave rule).
//  * stream sentinel 0x7FFF replaces pos<W checks.
//  * consume loop carries a scalar guard bound (defensive: converts any
//    unmodeled non-advance state into a wrong answer instead of a hang;
//    legal executions never hit it since every pass advances >=1 of <=128
//    entries per stream).
__global__ __launch_bounds__(512, 2) void sparse_attn_s8(
    const float* __restrict__ q,
    const __half* __restrict__ kh,
    const __half* __restrict__ vh,
    const unsigned short* __restrict__ idx2t,
    float* __restrict__ out)
{
    const int blk  = blockIdx.x;
    const int b    = blk & 3;              // XCD pinning: 2 XCDs per batch
    const int mc   = blk >> 2;             // 0..63
    const int tid  = threadIdx.x;
    const int wave = tid >> 6;             // 0..7
    const int lane = tid & 63;
    const int g    = lane >> 3;            // group (row) within wave: 0..7
    const int c    = lane & 7;             // dim-chunk: dims [c*8, c*8+8)
    const int rl   = wave * 8 + g;         // 0..63 local row
    const int m    = mc * RB + rl;

    __shared__ i4_t ring_k[3 * TT * 8];                        // 48 KB
    __shared__ i4_t ring_v[3 * TT * 8];                        // 48 KB
    __shared__ __align__(16) unsigned short idx2_s[W][RB];     // 16 KB

    const char* kb = (const char*)(kh + (size_t)b * M * D);
    const char* vb = (const char*)(vh + (size_t)b * M * D);

    // staging: tile = 16 KB K + 16 KB V; per wave 2+2 gl_lds of 1 KB, linear.
    auto stage = [&](int u) {
        const int s = u % 3;
        const size_t tb = (size_t)u * 16384;
        const int off = wave * 2048;
        const char* ks = kb + tb + off + lane * 16;
        const char* vs = vb + tb + off + lane * 16;
        char* kd = (char*)ring_k + s * 16384 + off;
        char* vd = (char*)ring_v + s * 16384 + off;
        __builtin_amdgcn_global_load_lds((gptr_t)ks, (sptr_t)kd, 16, 0, 0);
        __builtin_amdgcn_global_load_lds((gptr_t)(ks + 1024), (sptr_t)(kd + 1024), 16, 0, 0);
        __builtin_amdgcn_global_load_lds((gptr_t)vs, (sptr_t)vd, 16, 0, 0);
        __builtin_amdgcn_global_load_lds((gptr_t)(vs + 1024), (sptr_t)(vd + 1024), 16, 0, 0);
    };

    // idx staging: [pos][64 rows] u16; per wave 16 pos-rows = 2 gl_lds.
    {
        const int p0 = wave * 16;
        #pragma unroll
        for (int i = 0; i < 2; ++i) {
            const int pr = p0 + i * 8 + (lane >> 3);
            const size_t so = ((size_t)pr * M + (size_t)mc * RB + (lane & 7) * 8) * 2;
            __builtin_amdgcn_global_load_lds((gptr_t)((const char*)idx2t + so),
                (sptr_t)&idx2_s[p0 + i * 8][0], 16, 0, 0);
        }
    }
    stage(0);
    stage(1);

    // q fragment: dims [c*8, c*8+8) as 4x half2 for fdot2
    const float* qrow = q + ((size_t)b * M + m) * D + c * 8;
    const float4 qa = ((const float4*)qrow)[0];
    const float4 qc = ((const float4*)qrow)[1];
    h2_t qh[4];
    qh[0] = (h2_t){(_Float16)qa.x, (_Float16)qa.y};
    qh[1] = (h2_t){(_Float16)qa.z, (_Float16)qa.w};
    qh[2] = (h2_t){(_Float16)qc.x, (_Float16)qc.y};
    qh[3] = (h2_t){(_Float16)qc.z, (_Float16)qc.w};

    asm volatile("s_waitcnt vmcnt(0)" ::: "memory");
    __syncthreads();                       // idx + tiles 0,1 resident (all waves)

    float acc[8] = {0, 0, 0, 0, 0, 0, 0, 0};
    float mrun = -1e30f;
    float l = 0.f;

    int pos = 0;
    int cur = idx2_s[0][rl];               // group-uniform broadcast

    for (int t = 0; t < NTT; ++t) {
        if (t + 2 < NTT) stage(t + 2);     // lands during consume(t)

        const int s0 = (t % 3) * (TT * 8);         // i4 index of slot t
        const int s1 = ((t + 1) % 3) * (TT * 8);   // slot t+1

        // consume: forced tile t, opportunistic t+1 (resident window)
        for (int guard = 0; guard < W + 2 && __any((cur >> 7) <= t); ++guard) {
            const bool adv = ((cur >> 7) <= t + 1);
            if (adv) {
                const int pn  = pos + 1;
                const int pc  = (pn < W) ? pn : 0;
                const int nv  = idx2_s[pc][rl];
                const int nxt = (pn < W) ? nv : 0x7FFF;   // sentinel: done
                const int r   = cur & (TT - 1);
                const bool hi = (cur >> 7) > t;
                const int ko  = (hi ? s1 : s0) + r * 8 + c;
                union { i4_t v; h2_t h[4]; } uk, uv;
                uk.v = ring_k[ko];
                float part = __builtin_amdgcn_fdot2(uk.h[0], qh[0], 0.f, false);
                part = __builtin_amdgcn_fdot2(uk.h[1], qh[1], part, false);
                part = __builtin_amdgcn_fdot2(uk.h[2], qh[2], part, false);
                part = __builtin_amdgcn_fdot2(uk.h[3], qh[3], part, false);
                part = dpp_add<0xB1>(part);    // xor1 (quad_perm 1,0,3,2)
                part = dpp_add<0x4E>(part);    // xor2 (quad_perm 2,3,0,1)
                part = dpp_add<0x141>(part);   // cross-quad (row_half_mirror)
                float d = part - mrun;
                if (d > 8.0f) {                // defer-max: rare rescale
                    const float sc_ = __expf(-d);
                    l *= sc_;
                    #pragma unroll
                    for (int i2 = 0; i2 < 8; ++i2) acc[i2] *= sc_;
                    mrun = part;
                    d = 0.f;
                }
                const float pw = __expf(d);    // bounded by e^8
                l += pw;
                uv.v = ring_v[ko];
                #pragma unroll
                for (int j = 0; j < 4; ++j) {
                    acc[2 * j]     += pw * (float)uv.h[j][0];
                    acc[2 * j + 1] += pw * (float)uv.h[j][1];
                }
                pos = pn;
                cur = nxt;
            }
        }

        if (t + 1 < NTT) {
            // own stage(t+2) done BEFORE barrier => after barrier ALL
            // waves' t+2 loads complete (cross-wave correctness key).
            asm volatile("s_waitcnt vmcnt(0)" ::: "memory");
            __builtin_amdgcn_s_barrier();
            asm volatile("" ::: "memory");
        }
    }

    const float inv = 1.0f / l;
    float* orow = out + ((size_t)b * M + m) * D + c * 8;
    ((float4*)orow)[0] = make_float4(acc[0] * inv, acc[1] * inv,
                                     acc[2] * inv, acc[3] * inv);
    ((float4*)orow)[1] = make_float4(acc[4] * inv, acc[5] * inv,
                                     acc[6] * inv, acc[7] * inv);
}

// ---- fallback fp32 kernel if workspace too small ----
__global__ __launch_bounds__(128) void sparse_attn_f32(
    const float* __restrict__ q,
    const float* __restrict__ k,
    const float* __restrict__ v,
    const int*   __restrict__ idx,
    float*       __restrict__ out)
{
    const int blk = blockIdx.x;
    const int b = blk & 3;
    const int m = blk >> 2;
    const int t = threadIdx.x;
    const int lane = t & 63;
    const int wave = t >> 6;
    const int ci = lane & 15;
    const int r  = lane >> 4;

    __shared__ int   idx_s[W];
    __shared__ float sc_s[W];
    __shared__ float red_s[4];
    __shared__ float4 opart_s[16];

    idx_s[t] = idx[m * W + t];
    const float4 qf = ((const float4*)(q + ((size_t)b * M + m) * D))[ci];
    __syncthreads();

    const float* kb = k + (size_t)b * M * D;
    const int wbase = wave * 64;

    #pragma unroll
    for (int j = 0; j < 16; ++j) {
        const int w = wbase + j * 4 + r;
        const float4 kv = ((const float4*)(kb + (size_t)idx_s[w] * D))[ci];
        float part = kv.x * qf.x + kv.y * qf.y + kv.z * qf.z + kv.w * qf.w;
        part += __shfl_xor(part, 1);
        part += __shfl_xor(part, 2);
        part += __shfl_xor(part, 4);
        part += __shfl_xor(part, 8);
        if (ci == 0) sc_s[w] = part;
    }
    __syncthreads();

    float logit = sc_s[t];
    float mx = logit;
    #pragma unroll
    for (int o = 1; o < 64; o <<= 1) mx = fmaxf(mx, __shfl_xor(mx, o));
    if (lane == 0) red_s[wave] = mx;
    __syncthreads();
    mx = fmaxf(red_s[0], red_s[1]);
    float e = __expf(logit - mx);
    float sm = e;
    #pragma unroll
    for (int o = 1; o < 64; o <<= 1) sm += __shfl_xor(sm, o);
    if (lane == 0) red_s[2 + wave] = sm;
    __syncthreads();
    const float inv_denom = 1.0f / (red_s[2] + red_s[3]);
    sc_s[t] = e * inv_denom;
    __syncthreads();

    const float* vb = v + (size_t)b * M * D;
    float4 acc = {0.f, 0.f, 0.f, 0.f};
    #pragma unroll
    for (int j = 0; j < 16; ++j) {
        const int w = wbase + j * 4 + r;
        const float p = sc_s[w];
        const float4 vv = ((const float4*)(vb + (size_t)idx_s[w] * D))[ci];
        acc.x += p * vv.x; acc.y += p * vv.y;
        acc.z += p * vv.z; acc.w += p * vv.w;
    }
    acc.x += __shfl_xor(acc.x, 16); acc.y += __shfl_xor(acc.y, 16);
    acc.z += __shfl_xor(acc.z, 16); acc.w += __shfl_xor(acc.w, 16);
    acc.x += __shfl_xor(acc.x, 32); acc.y += __shfl_xor(acc.y, 32);
    acc.z += __shfl_xor(acc.z, 32); acc.w += __shfl_xor(acc.w, 32);

    if (wave == 0 && r == 0) opart_s[ci] = acc;
    __syncthreads();
    if (wave == 1 && r == 0) {
        const float4 o0 = opart_s[ci];
        float4 res;
        res.x = o0.x + acc.x; res.y = o0.y + acc.y;
        res.z = o0.z + acc.z; res.w = o0.w + acc.w;
        ((float4*)(out + ((size_t)b * M + m) * D))[ci] = res;
    }
}

extern "C" void kernel_launch(void* const* d_in, const int* in_sizes, int n_in,
                              void* d_out, int out_size, void* d_ws, size_t ws_size,
                              hipStream_t stream) {
    const float* q = (const float*)d_in[0];
    const float* k = (const float*)d_in[1];
    const float* v = (const float*)d_in[2];
    const int* idx = (const int*)d_in[3];
    float* out = (float*)d_out;

    // workspace: kh (2 MB) | vh (2 MB) | idx2t u16 transposed (1 MB)
    const size_t sz_kv   = (size_t)NELEM * sizeof(__half);
    const size_t sz_idx2 = (size_t)M * W * sizeof(unsigned short);
    const size_t need = 2 * sz_kv + sz_idx2;
    if (ws_size >= need) {
        __half* khp = (__half*)d_ws;
        __half* vhp = khp + NELEM;
        unsigned short* idx2t = (unsigned short*)((char*)d_ws + 2 * sz_kv);

        const int n4 = NELEM / 4;
        const int cblk = (2 * n4 + 255) / 256;
        cvt_f32_f16_2<<<cblk, 256, 0, stream>>>((const float4*)k, (const float4*)v,
                                                (__half2*)khp, (__half2*)vhp, n4);
        bucket_idx_t<<<M / 4, 256, 0, stream>>>(idx, idx2t);
        sparse_attn_s8<<<B * M / RB, 512, 0, stream>>>(q, khp, vhp, idx2t, out);
    } else {
        sparse_attn_f32<<<B * M, 128, 0, stream>>>(q, k, v, idx, out);
    }
}